// Round 1
// baseline (6779.180 us; speedup 1.0000x reference)
//
#include <hip/hip_runtime.h>
#include <math.h>

#define B_ 32
#define T_ 48
#define ENC_ 1024
#define PRED_ 320
#define JH_ 512
#define NJ_ 1344
#define VOCAB_ 29
#define BLANK_ 28
#define MAXSYM_ 6
#define NSTEPS_ 288
#define GDEC 80
#define BDEC 512
#define GB 16      // batch per group
#define GBLK 40    // blocks per group
#define JPB 8      // LSTM j-cols per block
#define NJB 16     // joint blocks per group
#define VPB 32     // joint v-cols per joint block
#define HPAD 324   // padded h row

// ---- workspace layout (float indices) ----
// Stamped (value,step) pair buffers replace tag+data two-phase hops.
#define FPRE_OFF 0                // 786432
#define WE_OFF   786432           // 28*1280 = 35840
#define H0C2_OFF 822272           // + grp*10240 : 5120 (v,stamp) pairs per group
#define H1C2_OFF 842752           // + grp*10240
#define PL2_OFF  863232           // + grp*32768 + par*16384 : 8192 pairs per par
#define INT_OFF  928768           // int region: tagD only
#define NTAGS    1280             // tagD: grp*640 + lb*16
#define STAMPF   106496           // floats to zero starting at H0C2_OFF

__device__ __forceinline__ float sigm(float v) { return 1.0f / (1.0f + expf(-v)); }

__device__ __forceinline__ int  ld_i(const int* p)   { return __hip_atomic_load((int*)p, __ATOMIC_RELAXED, __HIP_MEMORY_SCOPE_AGENT); }
__device__ __forceinline__ void st_i(int* p, int v)  { __hip_atomic_store(p, v, __ATOMIC_RELAXED, __HIP_MEMORY_SCOPE_AGENT); }

// single-instruction 8B publish: (value, stamp) — self-validating datum
__device__ __forceinline__ void st_pair(float* p, float v, int stamp) {
    float2 x; x.x = v; x.y = __int_as_float(stamp);
    asm volatile("global_store_dwordx2 %0, %1, off sc0 sc1" :: "v"(p), "v"(x) : "memory");
}

// coherent fused 16B loads (bypass L1/L2, served at coherence point), wait folded in.
__device__ __forceinline__ void ldc4_5(const float* p0, const float* p1, const float* p2,
                                       const float* p3, const float* p4,
                                       float4& r0, float4& r1, float4& r2, float4& r3, float4& r4) {
    asm volatile("global_load_dwordx4 %0, %5, off sc0 sc1\n\t"
                 "global_load_dwordx4 %1, %6, off sc0 sc1\n\t"
                 "global_load_dwordx4 %2, %7, off sc0 sc1\n\t"
                 "global_load_dwordx4 %3, %8, off sc0 sc1\n\t"
                 "global_load_dwordx4 %4, %9, off sc0 sc1\n\t"
                 "s_waitcnt vmcnt(0)"
                 : "=&v"(r0), "=&v"(r1), "=&v"(r2), "=&v"(r3), "=&v"(r4)
                 : "v"(p0), "v"(p1), "v"(p2), "v"(p3), "v"(p4)
                 : "memory");
}
__device__ __forceinline__ void ldc4_8(const float* p0, const float* p1, const float* p2,
                                       const float* p3, const float* p4, const float* p5,
                                       const float* p6, const float* p7,
                                       float4& r0, float4& r1, float4& r2, float4& r3,
                                       float4& r4, float4& r5, float4& r6, float4& r7) {
    asm volatile("global_load_dwordx4 %0, %8, off sc0 sc1\n\t"
                 "global_load_dwordx4 %1, %9, off sc0 sc1\n\t"
                 "global_load_dwordx4 %2, %10, off sc0 sc1\n\t"
                 "global_load_dwordx4 %3, %11, off sc0 sc1\n\t"
                 "global_load_dwordx4 %4, %12, off sc0 sc1\n\t"
                 "global_load_dwordx4 %5, %13, off sc0 sc1\n\t"
                 "global_load_dwordx4 %6, %14, off sc0 sc1\n\t"
                 "global_load_dwordx4 %7, %15, off sc0 sc1\n\t"
                 "s_waitcnt vmcnt(0)"
                 : "=&v"(r0), "=&v"(r1), "=&v"(r2), "=&v"(r3),
                   "=&v"(r4), "=&v"(r5), "=&v"(r6), "=&v"(r7)
                 : "v"(p0), "v"(p1), "v"(p2), "v"(p3),
                   "v"(p4), "v"(p5), "v"(p6), "v"(p7)
                 : "memory");
}

#define OK2(r) (__float_as_int((r).y) == st && __float_as_int((r).w) == st)

// ---------------- init ----------------
__global__ void k_init(float* __restrict__ ws, int* __restrict__ out) {
    int idx = blockIdx.x * blockDim.x + threadIdx.x;
    int stride = gridDim.x * blockDim.x;
    for (int i = idx; i < STAMPF; i += stride) ws[H0C2_OFF + i] = 0.0f;  // stamp=0
    int* wi = (int*)ws;
    for (int i = idx; i < NTAGS; i += stride) wi[INT_OFF + i] = 0;
    for (int i = idx; i < B_*NSTEPS_; i += stride) out[i] = -1;  // lt
    if (idx < B_) out[B_*NSTEPS_ + idx] = 0;                     // lc
}

// ---------------- WE = emb @ Wi0^T  (28 x 1280) ----------------
__global__ __launch_bounds__(256) void k_we(const float* __restrict__ emb,
                                            const float* __restrict__ Wi0,
                                            float* __restrict__ ws) {
    __shared__ float es[PRED_];
    int l = blockIdx.x / 5;
    int rq = blockIdx.x % 5;
    int t = threadIdx.x;
    if (t < PRED_) es[t] = emb[l*PRED_ + t];
    if (t + 256 < PRED_) es[t + 256] = emb[l*PRED_ + t + 256];
    __syncthreads();
    int r = rq*256 + t;
    const float4* wr = (const float4*)(Wi0 + (size_t)r*PRED_);
    float acc = 0.0f;
    #pragma unroll 4
    for (int k4 = 0; k4 < PRED_/4; ++k4) {
        float4 w = wr[k4];
        acc += w.x*es[4*k4] + w.y*es[4*k4+1] + w.z*es[4*k4+2] + w.w*es[4*k4+3];
    }
    ws[WE_OFF + l*(4*PRED_) + r] = acc;
}

// ---------------- Fpre[b][t][j] = x[b,t]·Wj1[j,:1024] + bj1[j] ----------------
__global__ __launch_bounds__(256) void k_fpre(const float* __restrict__ x,
                                              const float* __restrict__ Wj1,
                                              const float* __restrict__ bj1,
                                              float* __restrict__ ws) {
    __shared__ float As[B_][129];
    __shared__ float Bs[64][129];
    int tt = blockIdx.x >> 3;
    int jb = blockIdx.x & 7;
    int tid = threadIdx.x;
    int b = tid >> 3, jq = tid & 7;
    float acc[8] = {0,0,0,0,0,0,0,0};
    for (int kc = 0; kc < ENC_; kc += 128) {
        for (int i = tid; i < B_*128; i += 256) {
            int bb = i >> 7, kk = i & 127;
            As[bb][kk] = x[((size_t)bb*T_ + tt)*ENC_ + kc + kk];
        }
        for (int i = tid; i < 64*128; i += 256) {
            int jj = i >> 7, kk = i & 127;
            Bs[jj][kk] = Wj1[((size_t)(jb*64 + jj))*NJ_ + kc + kk];
        }
        __syncthreads();
        for (int kk = 0; kk < 128; ++kk) {
            float a = As[b][kk];
            #pragma unroll
            for (int u = 0; u < 8; ++u) acc[u] += a * Bs[jq*8 + u][kk];
        }
        __syncthreads();
    }
    #pragma unroll
    for (int u = 0; u < 8; ++u) {
        int j = jb*64 + jq*8 + u;
        ws[FPRE_OFF + ((size_t)b*T_ + tt)*JH_ + j] = acc[u] + bj1[j];
    }
}

// ---------------- persistent decode: 2 independent batch-groups ----------------
__global__ __launch_bounds__(BDEC) void k_decode(
    const int* __restrict__ out_lens,
    const float* __restrict__ Wh0, const float* __restrict__ b0,
    const float* __restrict__ Wi1, const float* __restrict__ Wh1,
    const float* __restrict__ b1,
    const float* __restrict__ Wj1,
    const float* __restrict__ Wj2, const float* __restrict__ bj2,
    float* __restrict__ ws, int* __restrict__ out)
{
    const int tid = threadIdx.x;
    const int grp = blockIdx.x & 1;
    const int lb  = blockIdx.x >> 1;       // 0..39 group-local
    const int j0  = lb * JPB;              // LSTM col base
    const int v0  = lb * VPB;              // joint col base (lb<16)
    const int bb0 = grp * GB;              // global batch base

    float* H0C2g = ws + H0C2_OFF + grp*10240;
    float* H1C2g = ws + H1C2_OFF + grp*10240;
    float* PL2g  = ws + PL2_OFF  + grp*32768;
    const float* WE = ws + WE_OFF;
    const float* FP = ws + FPRE_OFF;
    int* wi = (int*)ws;
    int* tagD = wi + INT_OFF + grp*640;

    // ---- LDS ----
    __shared__ __align__(16) float wi1_s[32*HPAD];   // 40.5 KB (padded rows)
    __shared__ __align__(16) float hs0[GB*HPAD];     // 20.7 KB h0 candidates
    __shared__ __align__(16) float hs1[GB*HPAD];     // 20.7 KB h1 candidates
    __shared__ float P0a[32*GB], P0b[32*GB], P1s[32*GB];  // partial-GEMV caches
    __shared__ float parts[2048];
    __shared__ float parts2[2048];                   // P0b scratch (decoupled from parts)
    __shared__ float c0cur[128], c0cand[128], c1cur[128], c1cand[128];
    __shared__ float we_s[28][32];
    __shared__ float b0_s[32], b1_s[32], bj2_s[VOCAB_];
    __shared__ float wj2t[VPB*33];                   // [v][l] transposed
    __shared__ float jg_c[VPB*GB];                   // [v][gb]
    __shared__ float hid_s[GB*33];                   // [gb][v]
    __shared__ float logits_s[GB*33];
    __shared__ int ti_l[GB], last_l[GB], sa_l[GB], lc_l[GB], olen_s[GB];
    __shared__ unsigned s_masks[2];

    // ---- one-time preload ----
    for (int i = tid; i < 32*PRED_; i += BDEC) {
        int r = i / PRED_, c = i % PRED_;
        int g = r >> 3, jj = r & 7;
        wi1_s[r*HPAD + c] = Wi1[((size_t)(g*PRED_ + j0 + jj))*PRED_ + c];
    }
    if (lb < NJB) {
        for (int i = tid; i < VPB*32; i += BDEC) {
            int v = i >> 5, l = i & 31;
            wj2t[v*33 + l] = (l < VOCAB_) ? Wj2[(size_t)l*JH_ + v0 + v] : 0.f;
        }
    }
    for (int i = tid; i < 28*32; i += BDEC) {
        int ls = i >> 5, r = i & 31;
        int g = r >> 3, jj = r & 7;
        we_s[ls][r] = WE[(size_t)ls*(4*PRED_) + g*PRED_ + j0 + jj];
    }
    if (tid < 32) {
        int g = tid >> 3, jj = tid & 7;
        b0_s[tid] = b0[g*PRED_ + j0 + jj];
        b1_s[tid] = b1[g*PRED_ + j0 + jj];
    }
    if (tid < VOCAB_) bj2_s[tid] = bj2[tid];
    if (tid < GB) {
        olen_s[tid] = out_lens[bb0 + tid];
        ti_l[tid] = 0; last_l[tid] = -1; sa_l[tid] = 0; lc_l[tid] = 0;
    }
    for (int i = tid; i < GB*HPAD; i += BDEC) { hs0[i] = 0.f; hs1[i] = 0.f; }
    for (int i = tid; i < 32*GB; i += BDEC) P0a[i] = 0.f;
    if (tid < 128) { c0cur[tid]=0.f; c0cand[tid]=0.f; c1cur[tid]=0.f; c1cand[tid]=0.f; }
    __syncthreads();

    const int gb  = tid & 15;
    const int jl  = (tid >> 4) & 7;
    const int ks  = tid >> 7;         // 0..3 (k-chunks of 80)
    unsigned nbm = 0xffffu, actm = 0xffffu;

    // loop-invariant hop mappings
    int ga_g2[5], ga_col[5];
    #pragma unroll
    for (int q = 0; q < 5; ++q) {
        int e0 = (q*512 + tid) * 2;           // element index (pair)
        ga_g2[q]  = e0 / 320;
        ga_col[q] = e0 - ga_g2[q]*320;        // even
    }
    const int citem = tid & 255;              // (g2, lpair) for hopC
    const int chalf = tid >> 8;               // jb half
    const int cqbase = citem;                 // quad offset within jb region: g2*16+lp == citem

    for (int s = 0; s < NSTEPS_; ++s) {
        const int par = s & 1;
        const int st = s + 1;

        // ===== Fpre prefetch (joint blocks; ti known from prev decide) =====
        float f_reg = 0.f;
        {
            int v_ = tid >> 4, g2_ = tid & 15;
            if (lb < NJB && ((actm >> g2_) & 1)) {
                int tm = min(ti_l[g2_], T_ - 1);
                f_reg = FP[((size_t)(bb0+g2_)*T_ + tm)*JH_ + v0 + v_];
            }
        }

        if (nbm) {
            // ===== S1 finalize (pure LDS) + stamped publish =====
            if (tid < 128) {
                int g2 = tid & 15, jj = tid >> 4;
                if ((nbm >> g2) & 1) {
                    int ls = last_l[g2];
                    float gt[4];
                    #pragma unroll
                    for (int g = 0; g < 4; ++g) {
                        int r = g*8 + jj;
                        float v = P0a[r*GB + g2] + b0_s[r];
                        if (ls >= 0) v += we_s[ls][r];
                        gt[g] = v;
                    }
                    float cn = sigm(gt[1])*c0cur[tid] + sigm(gt[0])*tanhf(gt[2]);
                    float hn = sigm(gt[3])*tanhf(cn);
                    c0cand[tid] = cn;
                    st_pair(&H0C2g[(g2*PRED_ + j0 + jj)*2], hn, st);
                }
            }
            // ===== P1 = Wh1 · h1cur (streamed; covers H0C2 stamp flight) =====
            {
                const float* hr = &hs1[gb*HPAD];
                int k0 = ks * 80;
                float a0=0.f,a1=0.f,a2=0.f,a3=0.f;
                const float* w0 = Wh1 + ((size_t)(0*PRED_ + j0 + jl))*PRED_;
                const float* w1 = Wh1 + ((size_t)(1*PRED_ + j0 + jl))*PRED_;
                const float* w2 = Wh1 + ((size_t)(2*PRED_ + j0 + jl))*PRED_;
                const float* w3 = Wh1 + ((size_t)(3*PRED_ + j0 + jl))*PRED_;
                #pragma unroll 4
                for (int kk = k0; kk < k0 + 80; kk += 4) {
                    float4 h = *(const float4*)&hr[kk];
                    float4 q0 = *(const float4*)(w0 + kk);
                    float4 q1 = *(const float4*)(w1 + kk);
                    float4 q2 = *(const float4*)(w2 + kk);
                    float4 q3 = *(const float4*)(w3 + kk);
                    a0 += q0.x*h.x+q0.y*h.y+q0.z*h.z+q0.w*h.w;
                    a1 += q1.x*h.x+q1.y*h.y+q1.z*h.z+q1.w*h.w;
                    a2 += q2.x*h.x+q2.y*h.y+q2.z*h.z+q2.w*h.w;
                    a3 += q3.x*h.x+q3.y*h.y+q3.z*h.z+q3.w*h.w;
                }
                parts[((0*4+ks)*8+jl)*16+gb] = a0;
                parts[((1*4+ks)*8+jl)*16+gb] = a1;
                parts[((2*4+ks)*8+jl)*16+gb] = a2;
                parts[((3*4+ks)*8+jl)*16+gb] = a3;
            }
            __syncthreads();
            for (int i = tid; i < 32*GB; i += BDEC) {
                int r = i / GB, g2 = i % GB;
                P1s[r*GB + g2] = parts[((((r>>3)*4+0)*8)+(r&7))*16+g2]
                               + parts[((((r>>3)*4+1)*8)+(r&7))*16+g2]
                               + parts[((((r>>3)*4+2)*8)+(r&7))*16+g2]
                               + parts[((((r>>3)*4+3)*8)+(r&7))*16+g2];
            }
            // ===== hopA: single-RT stamped gather of h0cand =====
            {
                float4 r0,r1,r2,r3,r4;
                const float* a0 = H0C2g + (0*512+tid)*4;
                const float* a1 = H0C2g + (1*512+tid)*4;
                const float* a2 = H0C2g + (2*512+tid)*4;
                const float* a3 = H0C2g + (3*512+tid)*4;
                const float* a4 = H0C2g + (4*512+tid)*4;
                const bool n0=(nbm>>ga_g2[0])&1, n1=(nbm>>ga_g2[1])&1, n2=(nbm>>ga_g2[2])&1,
                           n3=(nbm>>ga_g2[3])&1, n4=(nbm>>ga_g2[4])&1;
                for (;;) {
                    ldc4_5(a0,a1,a2,a3,a4,r0,r1,r2,r3,r4);
                    bool ok = (!n0 || OK2(r0)) && (!n1 || OK2(r1)) && (!n2 || OK2(r2))
                           && (!n3 || OK2(r3)) && (!n4 || OK2(r4));
                    if (ok) break;
                    __builtin_amdgcn_s_sleep(1);
                }
                if (n0) *(float2*)&hs0[ga_g2[0]*HPAD + ga_col[0]] = make_float2(r0.x, r0.z);
                if (n1) *(float2*)&hs0[ga_g2[1]*HPAD + ga_col[1]] = make_float2(r1.x, r1.z);
                if (n2) *(float2*)&hs0[ga_g2[2]*HPAD + ga_col[2]] = make_float2(r2.x, r2.z);
                if (n3) *(float2*)&hs0[ga_g2[3]*HPAD + ga_col[3]] = make_float2(r3.x, r3.z);
                if (n4) *(float2*)&hs0[ga_g2[4]*HPAD + ga_col[4]] = make_float2(r4.x, r4.z);
            }
            __syncthreads();

            // ===== S2: Wi1·h0cand (LDS) =====
            {
                const float* hr = &hs0[gb*HPAD];
                int k0 = ks * 80;
                float a0=0.f,a1=0.f,a2=0.f,a3=0.f;
                #pragma unroll 4
                for (int kk = k0; kk < k0 + 80; kk += 4) {
                    float4 h = *(const float4*)&hr[kk];
                    float4 q0 = *(const float4*)&wi1_s[(0*8+jl)*HPAD + kk];
                    float4 q1 = *(const float4*)&wi1_s[(1*8+jl)*HPAD + kk];
                    float4 q2 = *(const float4*)&wi1_s[(2*8+jl)*HPAD + kk];
                    float4 q3 = *(const float4*)&wi1_s[(3*8+jl)*HPAD + kk];
                    a0 += q0.x*h.x+q0.y*h.y+q0.z*h.z+q0.w*h.w;
                    a1 += q1.x*h.x+q1.y*h.y+q1.z*h.z+q1.w*h.w;
                    a2 += q2.x*h.x+q2.y*h.y+q2.z*h.z+q2.w*h.w;
                    a3 += q3.x*h.x+q3.y*h.y+q3.z*h.z+q3.w*h.w;
                }
                parts[((0*4+ks)*8+jl)*16+gb] = a0;
                parts[((1*4+ks)*8+jl)*16+gb] = a1;
                parts[((2*4+ks)*8+jl)*16+gb] = a2;
                parts[((3*4+ks)*8+jl)*16+gb] = a3;
            }
            __syncthreads();
            // assemble gates1 + stamped publish h1cand
            if (tid < 128) {
                int g2 = tid & 15, jj = tid >> 4;
                if ((nbm >> g2) & 1) {
                    float gt[4];
                    #pragma unroll
                    for (int g = 0; g < 4; ++g) {
                        int r = g*8 + jj;
                        gt[g] = parts[((g*4+0)*8+jj)*16+g2] + parts[((g*4+1)*8+jj)*16+g2]
                              + parts[((g*4+2)*8+jj)*16+g2] + parts[((g*4+3)*8+jj)*16+g2]
                              + P1s[r*GB + g2] + b1_s[r];
                    }
                    float cn = sigm(gt[1])*c1cur[tid] + sigm(gt[0])*tanhf(gt[2]);
                    float hn = sigm(gt[3])*tanhf(cn);
                    c1cand[tid] = cn;
                    st_pair(&H1C2g[(g2*PRED_ + j0 + jj)*2], hn, st);
                }
            }
            // ===== P0b = Wh0 · h0cand (streamed into parts2; covers hopB flight) =====
            {
                const float* hr = &hs0[gb*HPAD];
                int k0 = ks * 80;
                float a0=0.f,a1=0.f,a2=0.f,a3=0.f;
                const float* w0 = Wh0 + ((size_t)(0*PRED_ + j0 + jl))*PRED_;
                const float* w1 = Wh0 + ((size_t)(1*PRED_ + j0 + jl))*PRED_;
                const float* w2 = Wh0 + ((size_t)(2*PRED_ + j0 + jl))*PRED_;
                const float* w3 = Wh0 + ((size_t)(3*PRED_ + j0 + jl))*PRED_;
                #pragma unroll 4
                for (int kk = k0; kk < k0 + 80; kk += 4) {
                    float4 h = *(const float4*)&hr[kk];
                    float4 q0 = *(const float4*)(w0 + kk);
                    float4 q1 = *(const float4*)(w1 + kk);
                    float4 q2 = *(const float4*)(w2 + kk);
                    float4 q3 = *(const float4*)(w3 + kk);
                    a0 += q0.x*h.x+q0.y*h.y+q0.z*h.z+q0.w*h.w;
                    a1 += q1.x*h.x+q1.y*h.y+q1.z*h.z+q1.w*h.w;
                    a2 += q2.x*h.x+q2.y*h.y+q2.z*h.z+q2.w*h.w;
                    a3 += q3.x*h.x+q3.y*h.y+q3.z*h.z+q3.w*h.w;
                }
                parts2[((0*4+ks)*8+jl)*16+gb] = a0;
                parts2[((1*4+ks)*8+jl)*16+gb] = a1;
                parts2[((2*4+ks)*8+jl)*16+gb] = a2;
                parts2[((3*4+ks)*8+jl)*16+gb] = a3;
            }
            // ===== hopB: single-RT stamped gather of h1cand =====
            {
                float4 r0,r1,r2,r3,r4;
                const float* a0 = H1C2g + (0*512+tid)*4;
                const float* a1 = H1C2g + (1*512+tid)*4;
                const float* a2 = H1C2g + (2*512+tid)*4;
                const float* a3 = H1C2g + (3*512+tid)*4;
                const float* a4 = H1C2g + (4*512+tid)*4;
                const bool n0=(nbm>>ga_g2[0])&1, n1=(nbm>>ga_g2[1])&1, n2=(nbm>>ga_g2[2])&1,
                           n3=(nbm>>ga_g2[3])&1, n4=(nbm>>ga_g2[4])&1;
                for (;;) {
                    ldc4_5(a0,a1,a2,a3,a4,r0,r1,r2,r3,r4);
                    bool ok = (!n0 || OK2(r0)) && (!n1 || OK2(r1)) && (!n2 || OK2(r2))
                           && (!n3 || OK2(r3)) && (!n4 || OK2(r4));
                    if (ok) break;
                    __builtin_amdgcn_s_sleep(1);
                }
                if (n0) *(float2*)&hs1[ga_g2[0]*HPAD + ga_col[0]] = make_float2(r0.x, r0.z);
                if (n1) *(float2*)&hs1[ga_g2[1]*HPAD + ga_col[1]] = make_float2(r1.x, r1.z);
                if (n2) *(float2*)&hs1[ga_g2[2]*HPAD + ga_col[2]] = make_float2(r2.x, r2.z);
                if (n3) *(float2*)&hs1[ga_g2[3]*HPAD + ga_col[3]] = make_float2(r3.x, r3.z);
                if (n4) *(float2*)&hs1[ga_g2[4]*HPAD + ga_col[4]] = make_float2(r4.x, r4.z);
            }
            __syncthreads();
        } else {
            // blank step: PL[par] overwrite needs step-(s-2) readers done
            if (lb < NJB) {
                if (tid < GBLK) { while (ld_i(&tagD[tid*16]) < s-1) __builtin_amdgcn_s_sleep(1); }
                __syncthreads();
            }
        }

        // ===== S3a: joint blocks: jg (if recomputed) + hid + stamped partial logits =====
        if (lb < NJB) {
            {
                int v = tid >> 4, g2 = tid & 15;
                if (nbm && ((nbm >> g2) & 1)) {
                    const float* hr = &hs1[g2*HPAD];
                    const float* wt = Wj1 + ((size_t)(v0 + v))*NJ_ + ENC_;
                    float p = 0.f;
                    #pragma unroll 4
                    for (int kk = 0; kk < PRED_; kk += 4) {
                        float4 w4 = *(const float4*)(wt + kk);
                        float4 h  = *(const float4*)&hr[kk];
                        p += w4.x*h.x + w4.y*h.y + w4.z*h.z + w4.w*h.w;
                    }
                    jg_c[v*GB + g2] = p;
                }
                if ((actm >> g2) & 1) {
                    float hv = f_reg + jg_c[v*GB + g2];
                    hid_s[g2*33 + v] = fmaxf(hv, 0.f);
                }
            }
            __syncthreads();
            {
                int g2 = tid >> 5, l = tid & 31;
                const float* hb = &hid_s[g2*33];
                float acc = 0.f;
                #pragma unroll 8
                for (int v = 0; v < VPB; ++v) acc += wj2t[v*33 + l] * hb[v];
                st_pair(&PL2g[par*16384 + (lb*512 + g2*32 + l)*2], acc, st);
            }
        }

        // ===== P0b reduce (parts2 stable since pre-hopB; barrier passed) =====
        if (nbm) {
            for (int i = tid; i < 32*GB; i += BDEC) {
                int r = i / GB, g2 = i % GB;
                P0b[r*GB + g2] = parts2[((((r>>3)*4+0)*8)+(r&7))*16+g2]
                               + parts2[((((r>>3)*4+1)*8)+(r&7))*16+g2]
                               + parts2[((((r>>3)*4+2)*8)+(r&7))*16+g2]
                               + parts2[((((r>>3)*4+3)*8)+(r&7))*16+g2];
            }
        }

        // ===== hopC: single-RT stamped gather + reduce of partial logits =====
        {
            const float* pb = PL2g + par*16384;
            const float* a0 = pb + ((chalf*8+0)*256 + cqbase)*4;
            const float* a1 = pb + ((chalf*8+1)*256 + cqbase)*4;
            const float* a2 = pb + ((chalf*8+2)*256 + cqbase)*4;
            const float* a3 = pb + ((chalf*8+3)*256 + cqbase)*4;
            const float* a4 = pb + ((chalf*8+4)*256 + cqbase)*4;
            const float* a5 = pb + ((chalf*8+5)*256 + cqbase)*4;
            const float* a6 = pb + ((chalf*8+6)*256 + cqbase)*4;
            const float* a7 = pb + ((chalf*8+7)*256 + cqbase)*4;
            float4 q0,q1,q2,q3,q4,q5,q6,q7;
            for (;;) {
                ldc4_8(a0,a1,a2,a3,a4,a5,a6,a7,q0,q1,q2,q3,q4,q5,q6,q7);
                bool ok = OK2(q0) && OK2(q1) && OK2(q2) && OK2(q3)
                       && OK2(q4) && OK2(q5) && OK2(q6) && OK2(q7);
                if (ok) break;
                __builtin_amdgcn_s_sleep(1);
            }
            float ax = ((q0.x+q1.x)+(q2.x+q3.x)) + ((q4.x+q5.x)+(q6.x+q7.x));
            float az = ((q0.z+q1.z)+(q2.z+q3.z)) + ((q4.z+q5.z)+(q6.z+q7.z));
            *(float2*)&parts[(chalf*256 + citem)*2] = make_float2(ax, az);
        }
        __syncthreads();
        if (tid < 256) {
            float vx = parts[tid*2]   + parts[(256+tid)*2];
            float vz = parts[tid*2+1] + parts[(256+tid)*2+1];
            int g2 = tid >> 4, l = (tid & 15)*2;
            logits_s[g2*33 + l]   = (l   < VOCAB_) ? vx + bj2_s[l]   : -1e30f;
            logits_s[g2*33 + l+1] = (l+1 < VOCAB_) ? vz + bj2_s[l+1] : -1e30f;
        }
        __syncthreads();

        // ===== local redundant decide (single wave + ballot) =====
        if (tid < 64) {
            bool nbb = false, actb = false;
            if (tid < GB && ((actm >> tid) & 1)) {
                const int g2 = tid;
                float best = -1e30f; int bi = 0;
                for (int l = 0; l < VOCAB_; ++l) {
                    float v = logits_s[g2*33 + l];
                    if (v > best) { best = v; bi = l; }
                }
                const int blankness = (bi == BLANK_) ? 1 : 0;
                int tiv = ti_l[g2] + blankness;
                if (tiv >= olen_s[g2]) {
                    ti_l[g2] = tiv;                      // frozen
                } else {
                    int notb = 1 - blankness;
                    int sav = blankness ? 0 : sa_l[g2];
                    int nl = last_l[g2];
                    int lcn = lc_l[g2];
                    if (notb) {
                        lcn += 1;
                        if (lb == g2) {                  // designated writer
                            int bglob = bb0 + g2;
                            if (lcn < NSTEPS_) st_i(&out[bglob*NSTEPS_ + lcn], bi);
                            st_i(&out[B_*NSTEPS_ + bglob], lcn);
                        }
                        nl = bi;
                        sav += 1;
                    }
                    if (sav >= MAXSYM_) { tiv += 1; sav = 0; }
                    ti_l[g2] = tiv; sa_l[g2] = sav; last_l[g2] = nl; lc_l[g2] = lcn;
                    nbb = (notb != 0); actb = true;
                }
            }
            unsigned long long bn = __ballot(nbb);
            unsigned long long ba = __ballot(actb);
            if (tid == 0) { s_masks[0] = (unsigned)bn; s_masks[1] = (unsigned)ba; }
        }
        __syncthreads();
        const unsigned nbm_new = s_masks[0];
        actm = s_masks[1];
        // commit accepted candidates + speculative P0
        if (tid < 128) {
            int g2 = tid & 15;
            if ((nbm_new >> g2) & 1) { c0cur[tid] = c0cand[tid]; c1cur[tid] = c1cand[tid]; }
        }
        for (int i = tid; i < 32*GB; i += BDEC) {
            if ((nbm_new >> (i % GB)) & 1) P0a[i] = P0b[i];
        }
        __syncthreads();
        nbm = nbm_new;
        if (tid == 0) st_i(&tagD[lb*16], s + 1);
        if (!actm) break;
    }
}

extern "C" void kernel_launch(void* const* d_in, const int* in_sizes, int n_in,
                              void* d_out, int out_size, void* d_ws, size_t ws_size,
                              hipStream_t stream) {
    const float* x    = (const float*)d_in[0];
    const int*   olen = (const int*)d_in[1];
    const float* emb  = (const float*)d_in[2];
    const float* Wi0  = (const float*)d_in[3];
    const float* Wh0  = (const float*)d_in[4];
    const float* b0   = (const float*)d_in[5];
    const float* Wi1  = (const float*)d_in[6];
    const float* Wh1  = (const float*)d_in[7];
    const float* b1   = (const float*)d_in[8];
    const float* Wj1  = (const float*)d_in[9];
    const float* bj1  = (const float*)d_in[10];
    const float* Wj2  = (const float*)d_in[11];
    const float* bj2  = (const float*)d_in[12];
    float* ws = (float*)d_ws;
    int* out = (int*)d_out;

    hipLaunchKernelGGL(k_init, dim3(256), dim3(256), 0, stream, ws, out);
    hipLaunchKernelGGL(k_we,   dim3(28*5), dim3(256), 0, stream, emb, Wi0, ws);
    hipLaunchKernelGGL(k_fpre, dim3(T_*8), dim3(256), 0, stream, x, Wj1, bj1, ws);
    hipLaunchKernelGGL(k_decode, dim3(GDEC), dim3(BDEC), 0, stream,
                       olen, Wh0, b0, Wi1, Wh1, b1, Wj1, Wj2, bj2, ws, out);
}